// Round 6
// baseline (137.257 us; speedup 1.0000x reference)
//
#include <hip/hip_runtime.h>

typedef __bf16 bf16;
typedef __bf16 bf16x8 __attribute__((ext_vector_type(8)));
typedef __bf16 bf16x4 __attribute__((ext_vector_type(4)));
typedef float  f32x4  __attribute__((ext_vector_type(4)));

constexpr int NCLUS  = 8;
constexpr int HDIM   = 256;
constexpr int DIN    = 36;
constexpr int SEGCAP = 16384;          // per-cluster index capacity (mean 8192)
constexpr int LSTR   = 264;            // LDS row stride bf16 — MUST be >= 256 (round-2 bug).
                                       // 528 B/row = 132 dw == 4 mod 32 -> 2-way banks (free).
constexpr int CURPAD = 32;             // cursor entries 128 B apart
constexpr int SCAT_BLKS = 64;          // 64 x 1024 threads = 65536 points
constexpr int PREP_ROWS = NCLUS * HDIM + NCLUS * 3 * HDIM + NCLUS * 3;   // 8216
constexpr int PREP_BLKS = (PREP_ROWS + 15) / 16;                          // 16 waves/block
constexpr int MAXT   = 160;            // tiles/cluster covered (mean 128)
constexpr int MLP_BLKS = NCLUS * MAXT; // c = blockIdx&7 -> cluster pinned to one XCD

// ---------------- workspace layout (bytes) ----------------
constexpr size_t OFF_ORDER = 4096;     // cursor occupies [0, 1024)
constexpr size_t OFF_PIN   = OFF_ORDER + (size_t)NCLUS * SEGCAP * 4;
constexpr size_t OFF_PMID  = OFF_PIN + (size_t)NCLUS * 64 * 256 * 2;
constexpr size_t OFF_PWOUT = OFF_PMID + (size_t)NCLUS * 3 * 256 * 256 * 2;  // 8*4096 bf16

// Fused setup: blocks [0,64) partition points by cluster; the rest weight-norm+pack.
// A-frag map (row m, element k): lane=((k&31)>>3)*16+(m&15), j=k&7,
//   idx = ((k>>5)*16 + (m>>4))*512 + lane*8 + j.   (wout: single 16-row tile, m=o<3)
__global__ __launch_bounds__(1024) void setup_kernel(
    const int* __restrict__ cid, int* __restrict__ cursor, int* __restrict__ order,
    const float* __restrict__ V_in,  const float* __restrict__ g_in,
    const float* __restrict__ V_mid, const float* __restrict__ g_mid,
    const float* __restrict__ V_out, const float* __restrict__ g_out,
    bf16* __restrict__ pin, bf16* __restrict__ pmid, bf16* __restrict__ pwout) {
    const int tid = threadIdx.x;
    const int wv = tid >> 6, lane = tid & 63;

    if (blockIdx.x < SCAT_BLKS) {
        __shared__ int bhist[NCLUS];
        __shared__ int wbase[16][NCLUS];
        __shared__ int gbase[NCLUS];
        const int i = blockIdx.x * 1024 + tid;
        const int c = cid[i];
        if (tid < NCLUS) bhist[tid] = 0;
        __syncthreads();
        unsigned long long masks[NCLUS];
#pragma unroll
        for (int cc = 0; cc < NCLUS; cc++) masks[cc] = __ballot(c == cc);
        const int rank = __popcll(masks[c] & ((1ull << lane) - 1ull));
        if (lane < NCLUS) wbase[wv][lane] = atomicAdd(&bhist[lane], __popcll(masks[lane]));
        __syncthreads();
        if (tid < NCLUS) gbase[tid] = atomicAdd(&cursor[tid * CURPAD], bhist[tid]);
        __syncthreads();
        const int pos = gbase[c] + wbase[wv][c] + rank;
        if (pos < SEGCAP) order[c * SEGCAP + pos] = i;
        return;
    }

    const int row = (blockIdx.x - SCAT_BLKS) * 16 + wv;
    if (row >= PREP_ROWS) return;

    if (row < NCLUS * HDIM) {                                // input layer: [C,H,36]
        const int c = row >> 8, m = row & 255;
        const float* vrow = V_in + (size_t)row * DIN;
        float v = (lane < DIN) ? vrow[lane] : 0.f;
        float ss = v * v;
#pragma unroll
        for (int off = 32; off; off >>= 1) ss += __shfl_xor(ss, off);
        const float scale = g_in[row] / sqrtf(ss);
        const int k = lane;
        const int fl = (((k & 31) >> 3) << 4) | (m & 15);
        const int idx = ((k >> 5) * 16 + (m >> 4)) * 512 + fl * 8 + (k & 7);
        pin[(size_t)c * 16384 + idx] = (bf16)(v * scale);
    } else if (row < NCLUS * HDIM + NCLUS * 3 * HDIM) {      // mid: [C,3,H,H]
        const int r2 = row - NCLUS * HDIM;
        const int cl = r2 >> 8, m = r2 & 255;
        const float4 v4 = *(const float4*)(V_mid + (size_t)r2 * 256 + lane * 4);
        float ss = v4.x * v4.x + v4.y * v4.y + v4.z * v4.z + v4.w * v4.w;
#pragma unroll
        for (int off = 32; off; off >>= 1) ss += __shfl_xor(ss, off);
        const float scale = g_mid[cl * 256 + m] / sqrtf(ss);
        const int k = lane * 4;
        const int fl = (((k & 31) >> 3) << 4) | (m & 15);
        const int idx = ((k >> 5) * 16 + (m >> 4)) * 512 + fl * 8 + (k & 7);
        bf16x4 o = { (bf16)(v4.x * scale), (bf16)(v4.y * scale),
                     (bf16)(v4.z * scale), (bf16)(v4.w * scale) };
        *(bf16x4*)(pmid + (size_t)cl * 65536 + idx) = o;     // idx%8 in {0,4} -> 8 B aligned
    } else {                                                 // out rows: [C,3,H] -> A-frag tile
        const int r3 = row - (NCLUS * HDIM + NCLUS * 3 * HDIM);  // 0..23
        const int c = r3 / 3, o = r3 % 3;                    // m = o (< 16, single tile)
        const float4 v4 = *(const float4*)(V_out + (size_t)r3 * 256 + lane * 4);
        float ss = v4.x * v4.x + v4.y * v4.y + v4.z * v4.z + v4.w * v4.w;
#pragma unroll
        for (int off = 32; off; off >>= 1) ss += __shfl_xor(ss, off);
        const float scale = g_out[r3] / sqrtf(ss);
        const int k = lane * 4;
        const int fl = (((k & 31) >> 3) << 4) | o;
        const int idx = (k >> 5) * 512 + fl * 8 + (k & 7);
        bf16x4 ov = { (bf16)(v4.x * scale), (bf16)(v4.y * scale),
                      (bf16)(v4.z * scale), (bf16)(v4.w * scale) };
        *(bf16x4*)(pwout + (size_t)c * 4096 + idx) = ov;
        // rows 3..15 of the tile stay poisoned -> D rows 3..15 garbage, never read.
    }
}

// One layer in place: H[64,256] = relu(W @ H^T)^T. A = weights (prepacked, L2-resident
// via cluster->XCD pinning), B = activations (LDS). Wave w owns outcols [64w,64w+64).
// BOTH operand streams register-pipelined 2 ksteps ahead (3-slot rotation): kstep k's
// MFMAs consume ds_read/global_load issued at k-2 -> ~154cyc of MFMA issue covers
// lgkm ~120-170cyc and L2 ~200cyc (round-5: unpipelined b-frags stalled each kstep).
// D: col(lane&15)=point, row(quad*4+reg)=outcol -> epilogue = 16 x ds_write_b64.
template <int KSTEPS>
__device__ __forceinline__ void layer_fused(bf16* __restrict__ buf,
                                            const bf16* __restrict__ wp,
                                            const float* __restrict__ bias,
                                            int lane, int w) {
    const int quad = lane >> 4, l15 = lane & 15;
    f32x4 acc[4][4];   // [mt][nt]
#pragma unroll
    for (int mt = 0; mt < 4; mt++)
#pragma unroll
        for (int nt = 0; nt < 4; nt++) acc[mt][nt] = (f32x4){0.f, 0.f, 0.f, 0.f};

    bf16x8 a[3][4], b[3][4];
#pragma unroll
    for (int mt = 0; mt < 4; mt++)
        a[0][mt] = *(const bf16x8*)(wp + (size_t)((0 * 16 + (4 * w + mt)) * 512 + lane * 8));
#pragma unroll
    for (int nt = 0; nt < 4; nt++)
        b[0][nt] = *(const bf16x8*)(buf + (nt * 16 + l15) * LSTR + 0 * 32 + quad * 8);
    if (KSTEPS > 1) {
#pragma unroll
        for (int mt = 0; mt < 4; mt++)
            a[1][mt] = *(const bf16x8*)(wp + (size_t)((1 * 16 + (4 * w + mt)) * 512 + lane * 8));
#pragma unroll
        for (int nt = 0; nt < 4; nt++)
            b[1][nt] = *(const bf16x8*)(buf + (nt * 16 + l15) * LSTR + 1 * 32 + quad * 8);
    }

#pragma unroll
    for (int ks = 0; ks < KSTEPS; ks++) {
        if (ks + 2 < KSTEPS) {
            const int kp = ks + 2, slot = (ks + 2) % 3;
#pragma unroll
            for (int mt = 0; mt < 4; mt++)
                a[slot][mt] =
                    *(const bf16x8*)(wp + (size_t)((kp * 16 + (4 * w + mt)) * 512 + lane * 8));
#pragma unroll
            for (int nt = 0; nt < 4; nt++)
                b[slot][nt] = *(const bf16x8*)(buf + (nt * 16 + l15) * LSTR + kp * 32 + quad * 8);
        }
        const int cur = ks % 3;
#pragma unroll
        for (int mt = 0; mt < 4; mt++)
#pragma unroll
            for (int nt = 0; nt < 4; nt++)
                acc[mt][nt] = __builtin_amdgcn_mfma_f32_16x16x32_bf16(a[cur][mt], b[cur][nt],
                                                                      acc[mt][nt], 0, 0, 0);
    }
    __syncthreads();   // all reads of buf done
#pragma unroll
    for (int mt = 0; mt < 4; mt++) {
        const int m0 = 64 * w + mt * 16 + quad * 4;
        const float4 bv = *(const float4*)(bias + m0);
#pragma unroll
        for (int nt = 0; nt < 4; nt++) {
            const int p = nt * 16 + l15;
            float v0 = acc[mt][nt][0] + bv.x, v1 = acc[mt][nt][1] + bv.y;
            float v2 = acc[mt][nt][2] + bv.z, v3 = acc[mt][nt][3] + bv.w;
            bf16x4 o = { (bf16)(v0 > 0.f ? v0 : 0.f), (bf16)(v1 > 0.f ? v1 : 0.f),
                         (bf16)(v2 > 0.f ? v2 : 0.f), (bf16)(v3 > 0.f ? v3 : 0.f) };
            *(bf16x4*)(buf + p * LSTR + m0) = o;   // 8-B aligned
        }
    }
    __syncthreads();   // buf ready for next layer
}

__global__ __launch_bounds__(256, 2) void mlp_kernel(
    const float* __restrict__ X,
    const float* __restrict__ b_in, const float* __restrict__ b_mid,
    const float* __restrict__ b_out,
    const int* __restrict__ counts, const int* __restrict__ order,
    const bf16* __restrict__ pin, const bf16* __restrict__ pmid,
    const bf16* __restrict__ pwout, float* __restrict__ out) {
    // Cluster->XCD pinning (round-5: FETCH 15.5 -> 4.4 MB, weights L2-resident).
    const int c = blockIdx.x & 7;
    const int tile = blockIdx.x >> 3;
    int count = counts[c * CURPAD];
    if (count > SEGCAP) count = SEGCAP;
    const int s0 = tile * 64;
    if (s0 >= count) return;

    __shared__ __align__(16) bf16 buf[64 * LSTR];   // 33792 B
    __shared__ int sidx[64];
    __shared__ float sx[192];

    const int tid = threadIdx.x;
    const int lane = tid & 63;
    const int w = tid >> 6;
    const int quad = lane >> 4, l15 = lane & 15;

    if (tid < 64) {
        const int g = s0 + tid;
        sidx[tid] = order[c * SEGCAP + (g < count ? g : s0)];
    }
    __syncthreads();
    if (tid < 192) sx[tid] = X[(size_t)sidx[tid / 3] * 3 + tid % 3];
    __syncthreads();

    // Positional encoding -> bf16, cols 36..63 zero (weights zero there too).
    // __sinf/__cosf: hw v_sin/v_cos, err ~1e-5 at |x|<=200 rad << bf16 resolution.
    for (int v = tid; v < 64 * 64; v += 256) {
        const int p = v >> 6, col = v & 63;
        float val = 0.f;
        if (col < DIN) {
            const int f = col / 6, j = col - f * 6;
            const float xx = sx[p * 3 + (j >= 3 ? j - 3 : j)] * (float)(1 << f);
            val = (j < 3) ? __sinf(xx) : __cosf(xx);
        }
        buf[p * LSTR + col] = (bf16)val;
    }
    __syncthreads();

    layer_fused<2>(buf, pin + (size_t)c * 16384, b_in + c * 256, lane, w);
    layer_fused<8>(buf, pmid + (size_t)(c * 3 + 0) * 65536, b_mid + (c * 3 + 0) * 256, lane, w);
    layer_fused<8>(buf, pmid + (size_t)(c * 3 + 1) * 65536, b_mid + (c * 3 + 1) * 256, lane, w);
    layer_fused<8>(buf, pmid + (size_t)(c * 3 + 2) * 65536, b_mid + (c * 3 + 2) * 256, lane, w);

    // Final 256 -> 3 + tanh via one 16x16 MFMA tile per wave (rows 0..2 valid).
    // Wave w takes points [16w, 16w+16): B-frags from buf, A = pwout (prepacked).
    {
        const bf16* wa = pwout + (size_t)c * 4096;
        f32x4 acc4 = (f32x4){0.f, 0.f, 0.f, 0.f};
#pragma unroll
        for (int ks = 0; ks < 8; ks++) {
            const bf16x8 af = *(const bf16x8*)(wa + ks * 512 + lane * 8);
            const bf16x8 bfr = *(const bf16x8*)(buf + (w * 16 + l15) * LSTR + ks * 32 + quad * 8);
            acc4 = __builtin_amdgcn_mfma_f32_16x16x32_bf16(af, bfr, acc4, 0, 0, 0);
        }
        // D: col(l15)=point, row(quad*4+i)=out-channel; channels 0..2 live in quad 0.
        if (quad == 0) {
            const int p = w * 16 + l15;
            if (s0 + p < count) {
                float* op = out + (size_t)sidx[p] * 3;
                op[0] = tanhf(acc4[0] + b_out[c * 3 + 0]);
                op[1] = tanhf(acc4[1] + b_out[c * 3 + 1]);
                op[2] = tanhf(acc4[2] + b_out[c * 3 + 2]);
            }
        }
    }
}

extern "C" void kernel_launch(void* const* d_in, const int* in_sizes, int n_in,
                              void* d_out, int out_size, void* d_ws, size_t ws_size,
                              hipStream_t stream) {
    const float* X     = (const float*)d_in[0];
    const int*   cid   = (const int*)d_in[1];
    const float* V_in  = (const float*)d_in[2];
    const float* g_in  = (const float*)d_in[3];
    const float* b_in  = (const float*)d_in[4];
    const float* V_mid = (const float*)d_in[5];
    const float* g_mid = (const float*)d_in[6];
    const float* b_mid = (const float*)d_in[7];
    const float* V_out = (const float*)d_in[8];
    const float* g_out = (const float*)d_in[9];
    const float* b_out = (const float*)d_in[10];
    float* out = (float*)d_out;

    char* ws = (char*)d_ws;
    int*   cursor = (int*)ws;                    // NCLUS entries, 128 B apart
    int*   order  = (int*)(ws + OFF_ORDER);
    bf16*  pin    = (bf16*)(ws + OFF_PIN);
    bf16*  pmid   = (bf16*)(ws + OFF_PMID);
    bf16*  pwout  = (bf16*)(ws + OFF_PWOUT);

    hipMemsetAsync(cursor, 0, NCLUS * CURPAD * sizeof(int), stream);
    setup_kernel<<<SCAT_BLKS + PREP_BLKS, 1024, 0, stream>>>(
        cid, cursor, order, V_in, g_in, V_mid, g_mid, V_out, g_out, pin, pmid, pwout);
    mlp_kernel<<<MLP_BLKS, 256, 0, stream>>>(X, b_in, b_mid, b_out, cursor, order,
                                             pin, pmid, pwout, out);
}

// Round 7
// 133.539 us; speedup vs baseline: 1.0278x; 1.0278x over previous
//
#include <hip/hip_runtime.h>

typedef __bf16 bf16;
typedef __bf16 bf16x8 __attribute__((ext_vector_type(8)));
typedef __bf16 bf16x4 __attribute__((ext_vector_type(4)));
typedef float  f32x4  __attribute__((ext_vector_type(4)));

constexpr int NCLUS  = 8;
constexpr int HDIM   = 256;
constexpr int DIN    = 36;
constexpr int SEGCAP = 16384;          // per-cluster index capacity (mean 8192)
constexpr int LSTR   = 264;            // LDS row stride bf16 >= 256 (round-2 bug guard)
constexpr int CURPAD = 32;             // cursor entries 128 B apart
constexpr int SCAT_BLKS = 64;
constexpr int PREP_ROWS = NCLUS * HDIM + NCLUS * 3 * HDIM + NCLUS * 3;   // 8216
constexpr int PREP_BLKS = (PREP_ROWS + 15) / 16;
constexpr int MAXT   = 160;
constexpr int MLP_BLKS = NCLUS * MAXT;
constexpr int BUFSZ  = 64 * LSTR;                    // one activation buffer (bf16 elems)
constexpr int DYN_LDS = 2 * BUFSZ * 2;               // 67584 B ping-pong, needs attr >64K

// ---------------- workspace layout (bytes) ----------------
constexpr size_t OFF_ORDER = 4096;
constexpr size_t OFF_PIN   = OFF_ORDER + (size_t)NCLUS * SEGCAP * 4;
constexpr size_t OFF_PMID  = OFF_PIN + (size_t)NCLUS * 64 * 256 * 2;
constexpr size_t OFF_PWOUT = OFF_PMID + (size_t)NCLUS * 3 * 256 * 256 * 2;

// Fused setup: blocks [0,64) partition points by cluster; the rest weight-norm+pack.
__global__ __launch_bounds__(1024) void setup_kernel(
    const int* __restrict__ cid, int* __restrict__ cursor, int* __restrict__ order,
    const float* __restrict__ V_in,  const float* __restrict__ g_in,
    const float* __restrict__ V_mid, const float* __restrict__ g_mid,
    const float* __restrict__ V_out, const float* __restrict__ g_out,
    bf16* __restrict__ pin, bf16* __restrict__ pmid, bf16* __restrict__ pwout) {
    const int tid = threadIdx.x;
    const int wv = tid >> 6, lane = tid & 63;

    if (blockIdx.x < SCAT_BLKS) {
        __shared__ int bhist[NCLUS];
        __shared__ int wbase[16][NCLUS];
        __shared__ int gbase[NCLUS];
        const int i = blockIdx.x * 1024 + tid;
        const int c = cid[i];
        if (tid < NCLUS) bhist[tid] = 0;
        __syncthreads();
        unsigned long long masks[NCLUS];
#pragma unroll
        for (int cc = 0; cc < NCLUS; cc++) masks[cc] = __ballot(c == cc);
        const int rank = __popcll(masks[c] & ((1ull << lane) - 1ull));
        if (lane < NCLUS) wbase[wv][lane] = atomicAdd(&bhist[lane], __popcll(masks[lane]));
        __syncthreads();
        if (tid < NCLUS) gbase[tid] = atomicAdd(&cursor[tid * CURPAD], bhist[tid]);
        __syncthreads();
        const int pos = gbase[c] + wbase[wv][c] + rank;
        if (pos < SEGCAP) order[c * SEGCAP + pos] = i;
        return;
    }

    const int row = (blockIdx.x - SCAT_BLKS) * 16 + wv;
    if (row >= PREP_ROWS) return;

    if (row < NCLUS * HDIM) {                                // input layer: [C,H,36]
        const int c = row >> 8, m = row & 255;
        const float* vrow = V_in + (size_t)row * DIN;
        float v = (lane < DIN) ? vrow[lane] : 0.f;
        float ss = v * v;
#pragma unroll
        for (int off = 32; off; off >>= 1) ss += __shfl_xor(ss, off);
        const float scale = g_in[row] / sqrtf(ss);
        const int k = lane;
        const int fl = (((k & 31) >> 3) << 4) | (m & 15);
        const int idx = ((k >> 5) * 16 + (m >> 4)) * 512 + fl * 8 + (k & 7);
        pin[(size_t)c * 16384 + idx] = (bf16)(v * scale);
    } else if (row < NCLUS * HDIM + NCLUS * 3 * HDIM) {      // mid: [C,3,H,H]
        const int r2 = row - NCLUS * HDIM;
        const int cl = r2 >> 8, m = r2 & 255;
        const float4 v4 = *(const float4*)(V_mid + (size_t)r2 * 256 + lane * 4);
        float ss = v4.x * v4.x + v4.y * v4.y + v4.z * v4.z + v4.w * v4.w;
#pragma unroll
        for (int off = 32; off; off >>= 1) ss += __shfl_xor(ss, off);
        const float scale = g_mid[cl * 256 + m] / sqrtf(ss);
        const int k = lane * 4;
        const int fl = (((k & 31) >> 3) << 4) | (m & 15);
        const int idx = ((k >> 5) * 16 + (m >> 4)) * 512 + fl * 8 + (k & 7);
        bf16x4 o = { (bf16)(v4.x * scale), (bf16)(v4.y * scale),
                     (bf16)(v4.z * scale), (bf16)(v4.w * scale) };
        *(bf16x4*)(pmid + (size_t)cl * 65536 + idx) = o;
    } else {                                                 // out rows: [C,3,H] -> A-frag tile
        const int r3 = row - (NCLUS * HDIM + NCLUS * 3 * HDIM);  // 0..23
        const int c = r3 / 3, o = r3 % 3;
        const float4 v4 = *(const float4*)(V_out + (size_t)r3 * 256 + lane * 4);
        float ss = v4.x * v4.x + v4.y * v4.y + v4.z * v4.z + v4.w * v4.w;
#pragma unroll
        for (int off = 32; off; off >>= 1) ss += __shfl_xor(ss, off);
        const float scale = g_out[r3] / sqrtf(ss);
        const int k = lane * 4;
        const int fl = (((k & 31) >> 3) << 4) | o;
        const int idx = (k >> 5) * 512 + fl * 8 + (k & 7);
        bf16x4 ov = { (bf16)(v4.x * scale), (bf16)(v4.y * scale),
                      (bf16)(v4.z * scale), (bf16)(v4.w * scale) };
        *(bf16x4*)(pwout + (size_t)c * 4096 + idx) = ov;
    }
}

// One layer, ping-pong: dst[64,256] = relu(W @ src^T)^T. A = weights (prepacked,
// L2-resident), B = activations (LDS src). Wave w owns outcols [64w,64w+64).
// A-frags software-pipelined 2 ksteps ahead (R5-proven). src/dst disjoint -> the
// WAR barrier is gone: ONE __syncthreads per layer (after writes). Round-5/6
// lockstep diagnosis: 2 barriers/layer re-aligned all waves into the same phase,
// serializing VALU/LDS/MFMA demand (sum ~ 0.8x wall).
template <int KSTEPS>
__device__ __forceinline__ void layer_fused(const bf16* __restrict__ src,
                                            bf16* __restrict__ dst,
                                            const bf16* __restrict__ wp,
                                            const float* __restrict__ bias,
                                            int lane, int w) {
    const int quad = lane >> 4, l15 = lane & 15;
    f32x4 acc[4][4];   // [mt][nt]
#pragma unroll
    for (int mt = 0; mt < 4; mt++)
#pragma unroll
        for (int nt = 0; nt < 4; nt++) acc[mt][nt] = (f32x4){0.f, 0.f, 0.f, 0.f};

    bf16x8 a[3][4];
#pragma unroll
    for (int mt = 0; mt < 4; mt++)
        a[0][mt] = *(const bf16x8*)(wp + (size_t)((0 * 16 + (4 * w + mt)) * 512 + lane * 8));
    if (KSTEPS > 1)
#pragma unroll
        for (int mt = 0; mt < 4; mt++)
            a[1][mt] = *(const bf16x8*)(wp + (size_t)((1 * 16 + (4 * w + mt)) * 512 + lane * 8));

#pragma unroll
    for (int ks = 0; ks < KSTEPS; ks++) {
        if (ks + 2 < KSTEPS) {
#pragma unroll
            for (int mt = 0; mt < 4; mt++)
                a[(ks + 2) % 3][mt] =
                    *(const bf16x8*)(wp + (size_t)(((ks + 2) * 16 + (4 * w + mt)) * 512 + lane * 8));
        }
        bf16x8 b[4];
#pragma unroll
        for (int nt = 0; nt < 4; nt++)
            b[nt] = *(const bf16x8*)(src + (nt * 16 + l15) * LSTR + ks * 32 + quad * 8);
#pragma unroll
        for (int mt = 0; mt < 4; mt++)
#pragma unroll
            for (int nt = 0; nt < 4; nt++)
                acc[mt][nt] = __builtin_amdgcn_mfma_f32_16x16x32_bf16(a[ks % 3][mt], b[nt],
                                                                      acc[mt][nt], 0, 0, 0);
    }
    // No barrier here: dst and src are disjoint buffers.
#pragma unroll
    for (int mt = 0; mt < 4; mt++) {
        const int m0 = 64 * w + mt * 16 + quad * 4;
        const float4 bv = *(const float4*)(bias + m0);
#pragma unroll
        for (int nt = 0; nt < 4; nt++) {
            const int p = nt * 16 + l15;
            float v0 = acc[mt][nt][0] + bv.x, v1 = acc[mt][nt][1] + bv.y;
            float v2 = acc[mt][nt][2] + bv.z, v3 = acc[mt][nt][3] + bv.w;
            bf16x4 o = { (bf16)(v0 > 0.f ? v0 : 0.f), (bf16)(v1 > 0.f ? v1 : 0.f),
                         (bf16)(v2 > 0.f ? v2 : 0.f), (bf16)(v3 > 0.f ? v3 : 0.f) };
            *(bf16x4*)(dst + p * LSTR + m0) = o;
        }
    }
    __syncthreads();   // dst complete before anyone reads it next layer
}

__global__ __launch_bounds__(256, 3) void mlp_kernel(
    const float* __restrict__ X,
    const float* __restrict__ b_in, const float* __restrict__ b_mid,
    const float* __restrict__ b_out,
    const int* __restrict__ counts, const int* __restrict__ order,
    const bf16* __restrict__ pin, const bf16* __restrict__ pmid,
    const bf16* __restrict__ pwout, float* __restrict__ out) {
    // Cluster->XCD pinning (round-5: FETCH 15.5 -> 4.4 MB).
    const int c = blockIdx.x & 7;
    const int tile = blockIdx.x >> 3;
    int count = counts[c * CURPAD];
    if (count > SEGCAP) count = SEGCAP;
    const int s0 = tile * 64;
    if (s0 >= count) return;

    extern __shared__ __align__(16) bf16 smem[];    // 2 x 33792 B ping-pong
    bf16* bufA = smem;
    bf16* bufB = smem + BUFSZ;
    __shared__ int sidx[64];
    __shared__ float sx[192];

    const int tid = threadIdx.x;
    const int lane = tid & 63;
    const int w = tid >> 6;
    const int quad = lane >> 4, l15 = lane & 15;

    if (tid < 64) {
        const int g = s0 + tid;
        sidx[tid] = order[c * SEGCAP + (g < count ? g : s0)];
    }
    __syncthreads();
    if (tid < 192) sx[tid] = X[(size_t)sidx[tid / 3] * 3 + tid % 3];
    __syncthreads();

    // Positional encoding -> bufA, cols 36..63 zero (weights zero there too).
    for (int v = tid; v < 64 * 64; v += 256) {
        const int p = v >> 6, col = v & 63;
        float val = 0.f;
        if (col < DIN) {
            const int f = col / 6, j = col - f * 6;
            const float xx = sx[p * 3 + (j >= 3 ? j - 3 : j)] * (float)(1 << f);
            val = (j < 3) ? __sinf(xx) : __cosf(xx);
        }
        bufA[p * LSTR + col] = (bf16)val;
    }
    __syncthreads();

    layer_fused<2>(bufA, bufB, pin + (size_t)c * 16384, b_in + c * 256, lane, w);
    layer_fused<8>(bufB, bufA, pmid + (size_t)(c * 3 + 0) * 65536, b_mid + (c * 3 + 0) * 256, lane, w);
    layer_fused<8>(bufA, bufB, pmid + (size_t)(c * 3 + 1) * 65536, b_mid + (c * 3 + 1) * 256, lane, w);
    layer_fused<8>(bufB, bufA, pmid + (size_t)(c * 3 + 2) * 65536, b_mid + (c * 3 + 2) * 256, lane, w);

    // Final 256 -> 3 + tanh via one 16x16 MFMA tile per wave (rows 0..2 valid).
    {
        const bf16* wa = pwout + (size_t)c * 4096;
        f32x4 acc4 = (f32x4){0.f, 0.f, 0.f, 0.f};
#pragma unroll
        for (int ks = 0; ks < 8; ks++) {
            const bf16x8 af = *(const bf16x8*)(wa + ks * 512 + lane * 8);
            const bf16x8 bfr = *(const bf16x8*)(bufA + (w * 16 + l15) * LSTR + ks * 32 + quad * 8);
            acc4 = __builtin_amdgcn_mfma_f32_16x16x32_bf16(af, bfr, acc4, 0, 0, 0);
        }
        if (quad == 0) {
            const int p = w * 16 + l15;
            if (s0 + p < count) {
                float* op = out + (size_t)sidx[p] * 3;
                op[0] = tanhf(acc4[0] + b_out[c * 3 + 0]);
                op[1] = tanhf(acc4[1] + b_out[c * 3 + 1]);
                op[2] = tanhf(acc4[2] + b_out[c * 3 + 2]);
            }
        }
    }
}

extern "C" void kernel_launch(void* const* d_in, const int* in_sizes, int n_in,
                              void* d_out, int out_size, void* d_ws, size_t ws_size,
                              hipStream_t stream) {
    const float* X     = (const float*)d_in[0];
    const int*   cid   = (const int*)d_in[1];
    const float* V_in  = (const float*)d_in[2];
    const float* g_in  = (const float*)d_in[3];
    const float* b_in  = (const float*)d_in[4];
    const float* V_mid = (const float*)d_in[5];
    const float* g_mid = (const float*)d_in[6];
    const float* b_mid = (const float*)d_in[7];
    const float* V_out = (const float*)d_in[8];
    const float* g_out = (const float*)d_in[9];
    const float* b_out = (const float*)d_in[10];
    float* out = (float*)d_out;

    char* ws = (char*)d_ws;
    int*   cursor = (int*)ws;
    int*   order  = (int*)(ws + OFF_ORDER);
    bf16*  pin    = (bf16*)(ws + OFF_PIN);
    bf16*  pmid   = (bf16*)(ws + OFF_PMID);
    bf16*  pwout  = (bf16*)(ws + OFF_PWOUT);

    // Raise dynamic-LDS cap to 67584 B (not a stream op; graph-capture legal,
    // idempotent, called every launch per no-static-guards rule).
    hipFuncSetAttribute((const void*)mlp_kernel,
                        hipFuncAttributeMaxDynamicSharedMemorySize, DYN_LDS);

    hipMemsetAsync(cursor, 0, NCLUS * CURPAD * sizeof(int), stream);
    setup_kernel<<<SCAT_BLKS + PREP_BLKS, 1024, 0, stream>>>(
        cid, cursor, order, V_in, g_in, V_mid, g_mid, V_out, g_out, pin, pmid, pwout);
    mlp_kernel<<<MLP_BLKS, 256, DYN_LDS, stream>>>(X, b_in, b_mid, b_out, cursor, order,
                                                   pin, pmid, pwout, out);
}

// Round 8
// 115.684 us; speedup vs baseline: 1.1865x; 1.1543x over previous
//
#include <hip/hip_runtime.h>

typedef __bf16 bf16;
typedef __bf16 bf16x8 __attribute__((ext_vector_type(8)));
typedef __bf16 bf16x4 __attribute__((ext_vector_type(4)));
typedef float  f32x4  __attribute__((ext_vector_type(4)));

constexpr int NCLUS  = 8;
constexpr int HDIM   = 256;
constexpr int DIN    = 36;
constexpr int SEGCAP = 16384;          // per-cluster index capacity (mean 8192)
constexpr int CURPAD = 32;             // cursor entries 128 B apart
constexpr int SCAT_BLKS = 64;
constexpr int PREP_ROWS = NCLUS * HDIM + NCLUS * 3 * HDIM + NCLUS * 3;   // 8216
constexpr int PREP_BLKS = (PREP_ROWS + 15) / 16;
constexpr int MAXT   = 160;
constexpr int MLP_BLKS = NCLUS * MAXT;

// Activation buffer: 64 x 256 bf16 = 32768 B EXACT (no pad, no extra LDS arrays).
// Bank conflicts broken by XOR swizzle on element bits 3..5:
//   elem(p, col) = p*256 + (col ^ ((p & 7) << 3))
// Preserves col bits 0..2 -> any 8-elem-aligned (b128) or 4-elem-aligned (b64)
// access stays contiguous within its granule. b128 reads: 2-way (free);
// epilogue b64 writes: 4-way = the 512B/wave minimum. Goal: static LDS <= 32 KB
// (R5-R7 show dur*occ ~ const and residency ~2 blocks/CU -- consistent with a
// coarse LDS allocation granule rounding 34816 up past 2 granules).
__device__ __forceinline__ int swz(int p, int col) {
    return p * 256 + (col ^ ((p & 7) << 3));
}

// ---------------- workspace layout (bytes) ----------------
constexpr size_t OFF_ORDER = 4096;
constexpr size_t OFF_PIN   = OFF_ORDER + (size_t)NCLUS * SEGCAP * 4;
constexpr size_t OFF_PMID  = OFF_PIN + (size_t)NCLUS * 64 * 256 * 2;
constexpr size_t OFF_PWOUT = OFF_PMID + (size_t)NCLUS * 3 * 256 * 256 * 2;

// Fused setup: blocks [0,64) partition points by cluster; the rest weight-norm+pack.
__global__ __launch_bounds__(1024) void setup_kernel(
    const int* __restrict__ cid, int* __restrict__ cursor, int* __restrict__ order,
    const float* __restrict__ V_in,  const float* __restrict__ g_in,
    const float* __restrict__ V_mid, const float* __restrict__ g_mid,
    const float* __restrict__ V_out, const float* __restrict__ g_out,
    bf16* __restrict__ pin, bf16* __restrict__ pmid, bf16* __restrict__ pwout) {
    const int tid = threadIdx.x;
    const int wv = tid >> 6, lane = tid & 63;

    if (blockIdx.x < SCAT_BLKS) {
        __shared__ int bhist[NCLUS];
        __shared__ int wbase[16][NCLUS];
        __shared__ int gbase[NCLUS];
        const int i = blockIdx.x * 1024 + tid;
        const int c = cid[i];
        if (tid < NCLUS) bhist[tid] = 0;
        __syncthreads();
        unsigned long long masks[NCLUS];
#pragma unroll
        for (int cc = 0; cc < NCLUS; cc++) masks[cc] = __ballot(c == cc);
        const int rank = __popcll(masks[c] & ((1ull << lane) - 1ull));
        if (lane < NCLUS) wbase[wv][lane] = atomicAdd(&bhist[lane], __popcll(masks[lane]));
        __syncthreads();
        if (tid < NCLUS) gbase[tid] = atomicAdd(&cursor[tid * CURPAD], bhist[tid]);
        __syncthreads();
        const int pos = gbase[c] + wbase[wv][c] + rank;
        if (pos < SEGCAP) order[c * SEGCAP + pos] = i;
        return;
    }

    const int row = (blockIdx.x - SCAT_BLKS) * 16 + wv;
    if (row >= PREP_ROWS) return;

    if (row < NCLUS * HDIM) {                                // input layer: [C,H,36]
        const int c = row >> 8, m = row & 255;
        const float* vrow = V_in + (size_t)row * DIN;
        float v = (lane < DIN) ? vrow[lane] : 0.f;
        float ss = v * v;
#pragma unroll
        for (int off = 32; off; off >>= 1) ss += __shfl_xor(ss, off);
        const float scale = g_in[row] / sqrtf(ss);
        const int k = lane;
        const int fl = (((k & 31) >> 3) << 4) | (m & 15);
        const int idx = ((k >> 5) * 16 + (m >> 4)) * 512 + fl * 8 + (k & 7);
        pin[(size_t)c * 16384 + idx] = (bf16)(v * scale);
    } else if (row < NCLUS * HDIM + NCLUS * 3 * HDIM) {      // mid: [C,3,H,H]
        const int r2 = row - NCLUS * HDIM;
        const int cl = r2 >> 8, m = r2 & 255;
        const float4 v4 = *(const float4*)(V_mid + (size_t)r2 * 256 + lane * 4);
        float ss = v4.x * v4.x + v4.y * v4.y + v4.z * v4.z + v4.w * v4.w;
#pragma unroll
        for (int off = 32; off; off >>= 1) ss += __shfl_xor(ss, off);
        const float scale = g_mid[cl * 256 + m] / sqrtf(ss);
        const int k = lane * 4;
        const int fl = (((k & 31) >> 3) << 4) | (m & 15);
        const int idx = ((k >> 5) * 16 + (m >> 4)) * 512 + fl * 8 + (k & 7);
        bf16x4 o = { (bf16)(v4.x * scale), (bf16)(v4.y * scale),
                     (bf16)(v4.z * scale), (bf16)(v4.w * scale) };
        *(bf16x4*)(pmid + (size_t)cl * 65536 + idx) = o;
    } else {                                                 // out rows: [C,3,H] -> A-frag tile
        const int r3 = row - (NCLUS * HDIM + NCLUS * 3 * HDIM);  // 0..23
        const int c = r3 / 3, o = r3 % 3;
        const float4 v4 = *(const float4*)(V_out + (size_t)r3 * 256 + lane * 4);
        float ss = v4.x * v4.x + v4.y * v4.y + v4.z * v4.z + v4.w * v4.w;
#pragma unroll
        for (int off = 32; off; off >>= 1) ss += __shfl_xor(ss, off);
        const float scale = g_out[r3] / sqrtf(ss);
        const int k = lane * 4;
        const int fl = (((k & 31) >> 3) << 4) | o;
        const int idx = (k >> 5) * 512 + fl * 8 + (k & 7);
        bf16x4 ov = { (bf16)(v4.x * scale), (bf16)(v4.y * scale),
                      (bf16)(v4.z * scale), (bf16)(v4.w * scale) };
        *(bf16x4*)(pwout + (size_t)c * 4096 + idx) = ov;
    }
}

// One layer in place: H[64,256] = relu(W @ H^T)^T. A = weights (prepacked,
// L2-resident via cluster->XCD pinning), B = activations (swizzled LDS).
// Wave w owns outcols [64w,64w+64). A-frags software-pipelined 2 ksteps ahead.
// D: col(lane&15)=point, row(quad*4+reg)=outcol -> epilogue = 16 x ds_write_b64.
template <int KSTEPS>
__device__ __forceinline__ void layer_fused(bf16* __restrict__ buf,
                                            const bf16* __restrict__ wp,
                                            const float* __restrict__ bias,
                                            int lane, int w) {
    const int quad = lane >> 4, l15 = lane & 15;
    f32x4 acc[4][4];   // [mt][nt]
#pragma unroll
    for (int mt = 0; mt < 4; mt++)
#pragma unroll
        for (int nt = 0; nt < 4; nt++) acc[mt][nt] = (f32x4){0.f, 0.f, 0.f, 0.f};

    bf16x8 a[3][4];
#pragma unroll
    for (int mt = 0; mt < 4; mt++)
        a[0][mt] = *(const bf16x8*)(wp + (size_t)((0 * 16 + (4 * w + mt)) * 512 + lane * 8));
    if (KSTEPS > 1)
#pragma unroll
        for (int mt = 0; mt < 4; mt++)
            a[1][mt] = *(const bf16x8*)(wp + (size_t)((1 * 16 + (4 * w + mt)) * 512 + lane * 8));

#pragma unroll
    for (int ks = 0; ks < KSTEPS; ks++) {
        if (ks + 2 < KSTEPS) {
#pragma unroll
            for (int mt = 0; mt < 4; mt++)
                a[(ks + 2) % 3][mt] =
                    *(const bf16x8*)(wp + (size_t)(((ks + 2) * 16 + (4 * w + mt)) * 512 + lane * 8));
        }
        bf16x8 b[4];
#pragma unroll
        for (int nt = 0; nt < 4; nt++)
            b[nt] = *(const bf16x8*)(buf + swz(nt * 16 + l15, ks * 32 + quad * 8));
#pragma unroll
        for (int mt = 0; mt < 4; mt++)
#pragma unroll
            for (int nt = 0; nt < 4; nt++)
                acc[mt][nt] = __builtin_amdgcn_mfma_f32_16x16x32_bf16(a[ks % 3][mt], b[nt],
                                                                      acc[mt][nt], 0, 0, 0);
    }
    __syncthreads();   // all reads of buf done
#pragma unroll
    for (int mt = 0; mt < 4; mt++) {
        const int m0 = 64 * w + mt * 16 + quad * 4;
        const float4 bv = *(const float4*)(bias + m0);
#pragma unroll
        for (int nt = 0; nt < 4; nt++) {
            const int p = nt * 16 + l15;
            float v0 = acc[mt][nt][0] + bv.x, v1 = acc[mt][nt][1] + bv.y;
            float v2 = acc[mt][nt][2] + bv.z, v3 = acc[mt][nt][3] + bv.w;
            bf16x4 o = { (bf16)(v0 > 0.f ? v0 : 0.f), (bf16)(v1 > 0.f ? v1 : 0.f),
                         (bf16)(v2 > 0.f ? v2 : 0.f), (bf16)(v3 > 0.f ? v3 : 0.f) };
            *(bf16x4*)(buf + swz(p, m0)) = o;   // 8-B aligned (m0 % 4 == 0, swz keeps bits 0..2)
        }
    }
    __syncthreads();   // buf ready for next layer
}

__global__ __launch_bounds__(256, 3) void mlp_kernel(
    const float* __restrict__ X,
    const float* __restrict__ b_in, const float* __restrict__ b_mid,
    const float* __restrict__ b_out,
    const int* __restrict__ counts, const int* __restrict__ order,
    const bf16* __restrict__ pin, const bf16* __restrict__ pmid,
    const bf16* __restrict__ pwout, float* __restrict__ out) {
    // Cluster->XCD pinning (round-5: FETCH 15.5 -> 4.4 MB).
    const int c = blockIdx.x & 7;
    const int tile = blockIdx.x >> 3;
    int count = counts[c * CURPAD];
    if (count > SEGCAP) count = SEGCAP;
    const int s0 = tile * 64;
    if (s0 >= count) return;

    __shared__ __align__(16) bf16 buf[64 * 256];    // 32768 B exact, the ONLY LDS

    const int tid = threadIdx.x;
    const int lane = tid & 63;
    const int w = tid >> 6;
    const int quad = lane >> 4, l15 = lane & 15;

    // Positional encoding, no LDS staging: thread t owns point p = t>>2,
    // cols [(t&3)*16, +16). order/X read straight from global (L2).
    {
        const int p = tid >> 2;
        const int g = s0 + p;
        const int oidx = order[c * SEGCAP + (g < count ? g : s0)];
        const float x0 = X[(size_t)oidx * 3 + 0];
        const float x1 = X[(size_t)oidx * 3 + 1];
        const float x2 = X[(size_t)oidx * 3 + 2];
        const int cb = (tid & 3) * 16;
        bf16 vals[16];
#pragma unroll
        for (int j = 0; j < 16; j++) {
            const int col = cb + j;
            float val = 0.f;
            if (col < DIN) {
                const int f = col / 6, r = col - f * 6;
                const float xi = (r == 0 || r == 3) ? x0 : ((r == 1 || r == 4) ? x1 : x2);
                const float xx = xi * (float)(1 << f);
                val = (r < 3) ? __sinf(xx) : __cosf(xx);
            }
            vals[j] = (bf16)val;
        }
        *(bf16x8*)(buf + swz(p, cb))     = *(const bf16x8*)&vals[0];
        *(bf16x8*)(buf + swz(p, cb + 8)) = *(const bf16x8*)&vals[8];
    }
    __syncthreads();

    layer_fused<2>(buf, pin + (size_t)c * 16384, b_in + c * 256, lane, w);
    layer_fused<8>(buf, pmid + (size_t)(c * 3 + 0) * 65536, b_mid + (c * 3 + 0) * 256, lane, w);
    layer_fused<8>(buf, pmid + (size_t)(c * 3 + 1) * 65536, b_mid + (c * 3 + 1) * 256, lane, w);
    layer_fused<8>(buf, pmid + (size_t)(c * 3 + 2) * 65536, b_mid + (c * 3 + 2) * 256, lane, w);

    // Final 256 -> 3 + tanh via one 16x16 MFMA tile per wave (rows 0..2 valid).
    {
        const bf16* wa = pwout + (size_t)c * 4096;
        f32x4 acc4 = (f32x4){0.f, 0.f, 0.f, 0.f};
#pragma unroll
        for (int ks = 0; ks < 8; ks++) {
            const bf16x8 af = *(const bf16x8*)(wa + ks * 512 + lane * 8);
            const bf16x8 bfr = *(const bf16x8*)(buf + swz(w * 16 + l15, ks * 32 + quad * 8));
            acc4 = __builtin_amdgcn_mfma_f32_16x16x32_bf16(af, bfr, acc4, 0, 0, 0);
        }
        if (quad == 0) {
            const int p = w * 16 + l15;
            if (s0 + p < count) {
                const int oidx = order[c * SEGCAP + s0 + p];
                float* op = out + (size_t)oidx * 3;
                op[0] = tanhf(acc4[0] + b_out[c * 3 + 0]);
                op[1] = tanhf(acc4[1] + b_out[c * 3 + 1]);
                op[2] = tanhf(acc4[2] + b_out[c * 3 + 2]);
            }
        }
    }
}

extern "C" void kernel_launch(void* const* d_in, const int* in_sizes, int n_in,
                              void* d_out, int out_size, void* d_ws, size_t ws_size,
                              hipStream_t stream) {
    const float* X     = (const float*)d_in[0];
    const int*   cid   = (const int*)d_in[1];
    const float* V_in  = (const float*)d_in[2];
    const float* g_in  = (const float*)d_in[3];
    const float* b_in  = (const float*)d_in[4];
    const float* V_mid = (const float*)d_in[5];
    const float* g_mid = (const float*)d_in[6];
    const float* b_mid = (const float*)d_in[7];
    const float* V_out = (const float*)d_in[8];
    const float* g_out = (const float*)d_in[9];
    const float* b_out = (const float*)d_in[10];
    float* out = (float*)d_out;

    char* ws = (char*)d_ws;
    int*   cursor = (int*)ws;
    int*   order  = (int*)(ws + OFF_ORDER);
    bf16*  pin    = (bf16*)(ws + OFF_PIN);
    bf16*  pmid   = (bf16*)(ws + OFF_PMID);
    bf16*  pwout  = (bf16*)(ws + OFF_PWOUT);

    hipMemsetAsync(cursor, 0, NCLUS * CURPAD * sizeof(int), stream);
    setup_kernel<<<SCAT_BLKS + PREP_BLKS, 1024, 0, stream>>>(
        cid, cursor, order, V_in, g_in, V_mid, g_mid, V_out, g_out, pin, pmid, pwout);
    mlp_kernel<<<MLP_BLKS, 256, 0, stream>>>(X, b_in, b_mid, b_out, cursor, order,
                                             pin, pmid, pwout, out);
}